// Round 18
// baseline (1542.425 us; speedup 1.0000x reference)
//
#include <hip/hip_runtime.h>

typedef _Float16 h16;
typedef _Float16 h16x4 __attribute__((ext_vector_type(4)));
typedef _Float16 h16x8 __attribute__((ext_vector_type(8)));
typedef __fp16 fp16x2 __attribute__((ext_vector_type(2)));
typedef float f32x4 __attribute__((ext_vector_type(4)));
typedef float f32x16 __attribute__((ext_vector_type(16)));
typedef unsigned short u16;
typedef unsigned int u32;
typedef unsigned int u32x4 __attribute__((ext_vector_type(4)));

__device__ __forceinline__ f32x4 mfma16(h16x8 a, h16x8 b, f32x4 c) {
  return __builtin_amdgcn_mfma_f32_16x16x32_f16(a, b, c, 0, 0, 0);
}
__device__ __forceinline__ f32x16 mfma32(h16x8 a, h16x8 b, f32x16 c) {
  return __builtin_amdgcn_mfma_f32_32x32x16_f16(a, b, c, 0, 0, 0);
}
__device__ __forceinline__ float fexp2(float x) {
#if __has_builtin(__builtin_amdgcn_exp2f)
  return __builtin_amdgcn_exp2f(x);
#else
  return exp2f(x);
#endif
}
__device__ __forceinline__ u32 pkh(float a, float b) {
  fp16x2 t = __builtin_amdgcn_cvt_pkrtz(a, b);
  return __builtin_bit_cast(u32, t);
}

typedef const __attribute__((address_space(1))) void* gas_p;
typedef __attribute__((address_space(3))) void* las_p;
__device__ __forceinline__ void ldscp16(const void* g, void* l) {
  __builtin_amdgcn_global_load_lds((gas_p)g, (las_p)l, 16, 0, 0);
}
#define VMCNT(n) asm volatile("s_waitcnt vmcnt(" #n ")" ::: "memory")
#define SBAR() asm volatile("s_barrier" ::: "memory")

// ---------------- RMSNorm: f32 [2048][4096] -> f16 ----------------
__global__ __launch_bounds__(256) void rmsnorm_k(
    const float* __restrict__ x, const float* __restrict__ w, h16* __restrict__ out) {
  const int row = blockIdx.x, t = threadIdx.x;
  const float* xr = x + (size_t)row * 4096;
  float4 v[4];
  float ss = 0.f;
#pragma unroll
  for (int j = 0; j < 4; j++) {
    v[j] = *(const float4*)(xr + 4 * t + 1024 * j);
    ss += v[j].x * v[j].x + v[j].y * v[j].y + v[j].z * v[j].z + v[j].w * v[j].w;
  }
#pragma unroll
  for (int off = 1; off < 64; off <<= 1) ss += __shfl_xor(ss, off, 64);
  __shared__ float red[4];
  if ((t & 63) == 0) red[t >> 6] = ss;
  __syncthreads();
  float scale = rsqrtf((red[0] + red[1] + red[2] + red[3]) * (1.f / 4096.f) + 1e-6f);
  h16* orow = out + (size_t)row * 4096;
#pragma unroll
  for (int j = 0; j < 4; j++) {
    float4 wv = *(const float4*)(w + 4 * t + 1024 * j);
    h16x4 o;
    o[0] = (h16)(v[j].x * scale * wv.x);
    o[1] = (h16)(v[j].y * scale * wv.y);
    o[2] = (h16)(v[j].z * scale * wv.z);
    o[3] = (h16)(v[j].w * scale * wv.w);
    *(h16x4*)(orow + 4 * t + 1024 * j) = o;
  }
}

// ------- weight convert: f32 -> f16 tiled+swizzled LDS images -------
__global__ __launch_bounds__(256) void convw_k(
    const float* __restrict__ W, h16* __restrict__ out, int rowN, int ktiles) {
  __shared__ u16 timg[8192];
  const int t = threadIdx.x, b = blockIdx.x, kt = blockIdx.y;
  const float* src = W + (size_t)(kt * 64) * rowN + b * 128;
#pragma unroll
  for (int i = 0; i < 8; i++) {
    int c = t + (i << 8);
    int krow = c >> 5, nc = (c & 31) << 2;
    float4 v = *(const float4*)(src + (size_t)krow * rowN + nc);
    int kc = krow >> 3, e = krow & 7;
    float vals[4] = {v.x, v.y, v.z, v.w};
#pragma unroll
    for (int j = 0; j < 4; j++) {
      int m = nc + j;
      h16 hv = (h16)vals[j];
      timg[(m << 6) + ((kc ^ (m & 7)) << 3) + e] = __builtin_bit_cast(u16, hv);
    }
  }
  __syncthreads();
  uint4* dst = (uint4*)(out + ((size_t)(b * ktiles + kt) << 13));
  const uint4* s4 = (const uint4*)timg;
#pragma unroll
  for (int i = 0; i < 4; i++) dst[t + (i << 8)] = s4[t + (i << 8)];
}

// -------- GEMM v17: 256 thr, BM=BN=128, BK=64, 2 dbuf (64KB -> 2 blocks/CU) --------
// Counted prefetch dist-2: issue(t+2) after compute-barrier; tile top VMCNT(8)+SBAR.
// EPI: 1 f16; 2 f32=resid+acc; 3 f16=silu(uin)*acc; 4 f32+=acc;
//      5 split: col<4096 -> f16 outH with FUSED ROPE (resid=freqs table),
//               else f32 outF (col-4096, ld 2048)
template <int EPI>
__global__ __launch_bounds__(256, 2) void gemm_k(
    const h16* __restrict__ A, const h16* __restrict__ Wt,
    float* outF, h16* outH, const float* resid, const h16* uin,
    int K, int lda, int ldo, int no0) {
  __shared__ u16 lds[2][16384];  // per buf 32KB: A[128][64] @0, B[128][64] @16KB
  const int tid = threadIdx.x, lane = tid & 63;
  const int wv = tid >> 6, wr = wv >> 1, wc = wv & 1;
  const int g = lane >> 4, lr = lane & 15;
  const int m0 = blockIdx.y << 7, n0 = blockIdx.x << 7;
  const int ktiles = K >> 6;

  f32x4 acc[4][4];
#pragma unroll
  for (int i = 0; i < 4; i++)
#pragma unroll
    for (int j = 0; j < 4; j++) acc[i][j] = {0.f, 0.f, 0.f, 0.f};

  const h16* gB = Wt + (((size_t)blockIdx.x * ktiles) << 13) + tid * 8;

  auto issue = [&](int t) {
    char* base = (char*)lds[t & 1];
#pragma unroll
    for (int i = 0; i < 4; i++) {
      int c = tid + (i << 8);
      int r = c >> 3, ch = (c & 7) ^ ((c >> 3) & 7);
      ldscp16(A + (size_t)(m0 + r) * lda + t * 64 + (ch << 3), base + c * 16);
    }
#pragma unroll
    for (int i = 0; i < 4; i++)
      ldscp16(gB + ((size_t)t << 13) + (i << 11), base + 16384 + tid * 16 + (i << 12));
  };

  issue(0);
  issue(1);

  for (int t = 0; t < ktiles; ++t) {
    if (t + 1 < ktiles) { VMCNT(8); } else { VMCNT(0); }
    SBAR();
    const char* bp = (const char*)lds[t & 1];
#pragma unroll
    for (int ks = 0; ks < 2; ++ks) {
      h16x8 av[4], bv[4];
      const int cc = (ks << 2) + g;
#pragma unroll
      for (int f = 0; f < 4; f++) {
        int row = (wr << 6) + (f << 4) + lr;
        av[f] = *(const h16x8*)(bp + row * 128 + ((cc ^ (row & 7)) << 4));
        int nr = (wc << 6) + (f << 4) + lr;
        bv[f] = *(const h16x8*)(bp + 16384 + nr * 128 + ((cc ^ (nr & 7)) << 4));
      }
      __builtin_amdgcn_s_setprio(1);
#pragma unroll
      for (int fi = 0; fi < 4; fi++)
#pragma unroll
        for (int fj = 0; fj < 4; fj++)
          acc[fi][fj] = mfma16(av[fi], bv[fj], acc[fi][fj]);
      __builtin_amdgcn_s_setprio(0);
    }
    SBAR();
    if (t + 2 < ktiles) issue(t + 2);
  }
  // epilogue; C/D: col=lane&15, row=(lane>>4)*4+r
#pragma unroll
  for (int fi = 0; fi < 4; fi++) {
    const int row = m0 + (wr << 6) + (fi << 4) + (g << 2);
#pragma unroll
    for (int fj = 0; fj < 4; fj++) {
      const int col = no0 + n0 + (wc << 6) + (fj << 4) + lr;
#pragma unroll
      for (int r = 0; r < 4; r++) {
        float vl = acc[fi][fj][r];
        if constexpr (EPI == 5) {
          if (col < 4096) {
            // fused RoPE: partner element via lane^1 (col parity == lr parity)
            float pp = __shfl_xor(vl, 1, 64);
            const float* fc = resid + (size_t)(row + r) * 128 + (col & 126);
            float cs = fc[0], sn = fc[1];
            float o = (lr & 1) ? (pp * sn + vl * cs) : (vl * cs - pp * sn);
            outH[(size_t)(row + r) * 4096 + col] =
                (h16)(o * 0.12751743647239037f);  // 1/sqrt(128)*log2e
          } else {
            outF[(size_t)(row + r) * 2048 + (col - 4096)] = vl;
          }
        } else {
          size_t idx = (size_t)(row + r) * ldo + col;
          if constexpr (EPI == 1) outH[idx] = (h16)vl;
          else if constexpr (EPI == 2) outF[idx] = resid[idx] + vl;
          else if constexpr (EPI == 3) {
            float u = (float)uin[idx];
            outH[idx] = (h16)((u / (1.f + __expf(-u))) * vl);
          } else outF[idx] = outF[idx] + vl;
        }
      }
    }
  }
}

// ------- build new cache: f32 outs + f16 K [kvh][r][d] + f16 V^T [kvh][d][r] -------
__global__ __launch_bounds__(256) void cache_build_k(
    const float* __restrict__ oldK, const float* __restrict__ oldV,
    const float* __restrict__ kvraw, const float* __restrict__ freqs,
    float* __restrict__ outK, float* __restrict__ outV,
    h16* __restrict__ Kf, h16* __restrict__ Vt) {
  const int rt = blockIdx.x, kvh = blockIdx.y;
  const int r0 = rt * 64, tid = threadIdx.x;
  __shared__ u16 vtile[64][128];
#pragma unroll
  for (int it = 0; it < 16; ++it) {
    int s = tid + 256 * it;
    int rr = s >> 6, pp = s & 63;
    int r = r0 + rr;
    float k0, k1, v0, v1;
    if (r < 2048) {
      const float* kp = oldK + (size_t)(r + 2048) * 1024 + kvh * 128 + 2 * pp;
      k0 = kp[0]; k1 = kp[1];
      const float* vp = oldV + (size_t)(r + 2048) * 1024 + kvh * 128 + 2 * pp;
      v0 = vp[0]; v1 = vp[1];
    } else {
      int tpos = r - 2048;
      const float* kp = kvraw + (size_t)tpos * 2048 + kvh * 128 + 2 * pp;
      float x0 = kp[0], x1 = kp[1];
      float cs = freqs[tpos * 128 + 2 * pp], sn = freqs[tpos * 128 + 2 * pp + 1];
      k0 = x0 * cs - x1 * sn;
      k1 = x0 * sn + x1 * cs;
      const float* vp = kvraw + (size_t)tpos * 2048 + 1024 + kvh * 128 + 2 * pp;
      v0 = vp[0]; v1 = vp[1];
    }
    size_t oidx = (size_t)r * 1024 + kvh * 128 + 2 * pp;
    outK[oidx] = k0; outK[oidx + 1] = k1;
    outV[oidx] = v0; outV[oidx + 1] = v1;
    size_t kfi = (size_t)kvh * 524288 + (size_t)r * 128 + 2 * pp;
    Kf[kfi] = (h16)k0; Kf[kfi + 1] = (h16)k1;
    h16 h0 = (h16)v0, h1 = (h16)v1;
    vtile[rr][2 * pp] = __builtin_bit_cast(u16, h0);
    vtile[rr][2 * pp + 1] = __builtin_bit_cast(u16, h1);
  }
  __syncthreads();
#pragma unroll
  for (int it = 0; it < 4; ++it) {
    int c = tid + 256 * it;
    int d = c >> 3, rg = c & 7;
    u16 tmp[8];
#pragma unroll
    for (int u = 0; u < 8; u++) tmp[u] = vtile[rg * 8 + u][d];
    *(uint4*)((u16*)Vt + (size_t)kvh * 524288 + (size_t)d * 4096 + r0 + rg * 8) =
        *(uint4*)tmp;
  }
}

// -------- flash attention v5: 256 thr, QBLK=128, 2-buf, split counted vmcnt --------
__global__ __launch_bounds__(256, 2) void attn_k(
    const h16* __restrict__ Q, const h16* __restrict__ Kf,
    const h16* __restrict__ Vt, h16* __restrict__ O) {
  __shared__ u16 skv[2][16384];  // per buf: K[64 j][128 d] @0, V[128 d][64 j] @16KB
  const int qt = 15 - blockIdx.x, h = blockIdx.y;
  const int q0 = qt << 7, kvh = h >> 2;
  const int tid = threadIdx.x, w = tid >> 6, lane = tid & 63;
  const int lq = lane & 31, lh = lane >> 5;
  const h16* Kb = Kf + (size_t)kvh * 524288;
  const h16* Vb = Vt + (size_t)kvh * 524288;
  const int qg = q0 + w * 32 + lq;

  h16x8 qv[8];
  {
    const h16* qp = Q + (size_t)qg * 4096 + h * 128 + (lh << 3);
#pragma unroll
    for (int c = 0; c < 8; c++) qv[c] = *(const h16x8*)(qp + c * 16);
  }
  h16x8 hone;
#pragma unroll
  for (int i = 0; i < 8; i++) hone[i] = (h16)1.0f;
  f32x16 oa[4], ol2;
#pragma unroll
  for (int d = 0; d < 4; d++)
#pragma unroll
    for (int v = 0; v < 16; v++) oa[d][v] = 0.f;
#pragma unroll
  for (int v = 0; v < 16; v++) ol2[v] = 0.f;
  float m2 = -3e38f;
  const int ntiles = 34 + 2 * qt;

  const int jK = tid >> 4, kch = tid & 15;
  const h16* gK = Kb + (size_t)jK * 128 + ((kch ^ (jK & 15)) << 3);
  const int dV = tid >> 3, jch = tid & 7;
  const h16* gV = Vb + (size_t)dV * 4096 + ((jch ^ (dV & 7)) << 3);

  auto issueK = [&](int jt) {
    char* base = (char*)skv[jt & 1];
    const h16* s = gK + (size_t)(jt << 6) * 128;
#pragma unroll
    for (int i = 0; i < 4; i++)
      ldscp16(s + (size_t)i * 2048, base + tid * 16 + i * 4096);
  };
  auto issueV = [&](int jt) {
    char* base = (char*)skv[jt & 1] + 16384;
    const h16* s = gV + (jt << 6);
#pragma unroll
    for (int i = 0; i < 4; i++)
      ldscp16(s + (size_t)i * 131072, base + tid * 16 + i * 4096);
  };

  issueK(0); issueV(0);
  VMCNT(0);
  SBAR();

  for (int jt = 0; jt < ntiles; ++jt) {
    const char* bp = (const char*)skv[jt & 1];
    const bool more = (jt + 1 < ntiles);
    if (more) issueK(jt + 1);
    f32x16 st[2];
#pragma unroll
    for (int jb = 0; jb < 2; jb++) {
      f32x16 s;
#pragma unroll
      for (int v = 0; v < 16; v++) s[v] = 0.f;
      const int jr = jb * 32 + lq;
      __builtin_amdgcn_s_setprio(1);
#pragma unroll
      for (int kc = 0; kc < 8; kc++) {
        h16x8 ak =
            *(const h16x8*)(bp + jr * 256 + ((((kc << 1) + lh) ^ (jr & 15)) << 4));
        s = mfma32(ak, qv[kc], s);
      }
      __builtin_amdgcn_s_setprio(0);
      st[jb] = s;
    }
    if (more) issueV(jt + 1);
    if (jt >= ntiles - 2) {
      const int j0 = jt << 6;
#pragma unroll
      for (int jb = 0; jb < 2; jb++)
#pragma unroll
        for (int v = 0; v < 16; v++) {
          int j = j0 + jb * 32 + (v & 3) + (((v >> 2) & 3) << 3) + (lh << 2);
          if (j > 2048 + qg) st[jb][v] = -1e30f;
        }
    }
    float pm = fmaxf(st[0][0], st[0][1]);
#pragma unroll
    for (int v = 2; v < 16; v += 2) pm = fmaxf(fmaxf(st[0][v], st[0][v + 1]), pm);
#pragma unroll
    for (int v = 0; v < 16; v += 2) pm = fmaxf(fmaxf(st[1][v], st[1][v + 1]), pm);
    pm = fmaxf(pm, __shfl_xor(pm, 32, 64));
    if (__any(pm - m2 > 8.f)) {
      float mn = fmaxf(m2, pm);
      float al = fexp2(m2 - mn);
      m2 = mn;
#pragma unroll
      for (int d = 0; d < 4; d++) oa[d] *= al;
      ol2 *= al;
    }
    u32 pw[2][8];
#pragma unroll
    for (int jb = 0; jb < 2; jb++)
#pragma unroll
      for (int c = 0; c < 4; c++) {
        float p0 = fexp2(st[jb][4 * c] - m2);
        float p1 = fexp2(st[jb][4 * c + 1] - m2);
        float p2 = fexp2(st[jb][4 * c + 2] - m2);
        float p3 = fexp2(st[jb][4 * c + 3] - m2);
        pw[jb][2 * c] = pkh(p0, p1);
        pw[jb][2 * c + 1] = pkh(p2, p3);
      }
    h16x8 pb[4];
#pragma unroll
    for (int kc = 0; kc < 4; kc++) {
      const int jb = kc >> 1, cb = (kc & 1) << 1;
      u32 oa_ = pw[jb][2 * cb], ob_ = pw[jb][2 * cb + 1];
      u32 oc_ = pw[jb][2 * cb + 2], od_ = pw[jb][2 * cb + 3];
      u32 s0 = lh ? oa_ : oc_, s1 = lh ? ob_ : od_;
      u32 r0 = __shfl_xor(s0, 32, 64), r1 = __shfl_xor(s1, 32, 64);
      u32x4 wds = {lh ? r0 : oa_, lh ? r1 : ob_, lh ? oc_ : r0, lh ? od_ : r1};
      pb[kc] = __builtin_bit_cast(h16x8, wds);
    }
    // V(jt) ready gate: oldest-4 of {V(jt), K(jt+1), V(jt+1)} = V(jt)
    if (more) { VMCNT(8); } else { VMCNT(0); }
    __builtin_amdgcn_s_setprio(1);
#pragma unroll
    for (int d = 0; d < 4; d++) {
      const int dr = (d << 5) + lq;
#pragma unroll
      for (int kc = 0; kc < 4; kc++) {
        h16x8 av = *(const h16x8*)(bp + 16384 + dr * 128 +
                                   ((((kc << 1) + lh) ^ (dr & 7)) << 4));
        oa[d] = mfma32(av, pb[kc], oa[d]);
      }
    }
#pragma unroll
    for (int kc = 0; kc < 4; kc++) ol2 = mfma32(hone, pb[kc], ol2);
    __builtin_amdgcn_s_setprio(0);
    if (more) {
      VMCNT(4);  // K(jt+1) ready; V(jt+1) stays in flight across barrier
      SBAR();
    }
  }
  float rl = 1.f / ol2[0];
  h16* Op = O + (size_t)qg * 4096 + h * 128;
#pragma unroll
  for (int d = 0; d < 4; d++)
#pragma unroll
    for (int b = 0; b < 4; b++) {
      h16x4 ov;
#pragma unroll
      for (int i = 0; i < 4; i++) ov[i] = (h16)(oa[d][(b << 2) + i] * rl);
      *(h16x4*)(Op + (d << 5) + (b << 3) + (lh << 2)) = ov;
    }
}

extern "C" void kernel_launch(void* const* d_in, const int* in_sizes, int n_in,
                              void* d_out, int out_size, void* d_ws, size_t ws_size,
                              hipStream_t stream) {
  const float* x = (const float*)d_in[0];
  const float* freqs = (const float*)d_in[2];
  const float* oldK = (const float*)d_in[3];
  const float* oldV = (const float*)d_in[4];
  const float* wq = (const float*)d_in[5];
  const float* wk = (const float*)d_in[6];
  const float* wvp = (const float*)d_in[7];
  const float* wo = (const float*)d_in[8];
  const float* w1 = (const float*)d_in[9];
  const float* w2 = (const float*)d_in[10];
  const float* w3 = (const float*)d_in[11];
  const float* anw = (const float*)d_in[12];
  const float* fnw = (const float*)d_in[13];
  float* out = (float*)d_out;
  float* outK = out + 8388608;
  float* outV = out + 12582912;

  char* ws = (char*)d_ws;
  h16* xn = (h16*)(ws + 0);                // 16.78 MB f16 [2048][4096]
  h16* bufW = (h16*)(ws + 16777216);       // 58.72 MB tiled f16 weights (reused)
  float* hbuf = (float*)(ws + 75497472);   // 33.55 MB f32 [2048][4096]
  float* kvraw = (float*)(ws + 75497472);  // 16.78 MB f32 [2048][2048] (aliased)
  h16* kf = (h16*)(ws + 92274688);         //  8.39 MB
  h16* vt = (h16*)(ws + 100663296);        //  8.39 MB
  h16* ub = (h16*)(ws + 109051904);        // 58.72 MB f16 [2048][14336]
  h16* qraw = (h16*)(ws + 109051904);      // 16.78 MB (aliased in ub span)
  h16* attnb = (h16*)(ws + 125829120);     // 16.78 MB (aliased in ub span)

  // attention path
  rmsnorm_k<<<2048, 256, 0, stream>>>(x, anw, xn);
  convw_k<<<dim3(32, 64), 256, 0, stream>>>(wq, bufW, 4096, 64);
  convw_k<<<dim3(8, 64), 256, 0, stream>>>(wk, bufW + ((size_t)32 * 64 << 13), 1024, 64);
  convw_k<<<dim3(8, 64), 256, 0, stream>>>(wvp, bufW + ((size_t)40 * 64 << 13), 1024, 64);
  gemm_k<5><<<dim3(48, 16), 256, 0, stream>>>(xn, bufW, kvraw, qraw, freqs,
                                              nullptr, 4096, 4096, 0, 0);
  cache_build_k<<<dim3(64, 8), 256, 0, stream>>>(oldK, oldV, kvraw, freqs, outK,
                                                 outV, kf, vt);
  attn_k<<<dim3(16, 32), 256, 0, stream>>>(qraw, kf, vt, attnb);
  convw_k<<<dim3(32, 64), 256, 0, stream>>>(wo, bufW, 4096, 64);
  gemm_k<2><<<dim3(32, 16), 256, 0, stream>>>(attnb, bufW, hbuf, nullptr, x,
                                              nullptr, 4096, 4096, 4096, 0);
  // FFN path
  rmsnorm_k<<<2048, 256, 0, stream>>>(hbuf, fnw, xn);
  convw_k<<<dim3(56, 64), 256, 0, stream>>>(w1, bufW, 14336, 64);
  gemm_k<1><<<dim3(56, 16), 256, 0, stream>>>(xn, bufW, nullptr, ub, nullptr,
                                              nullptr, 4096, 4096, 14336, 0);
  convw_k<<<dim3(56, 64), 256, 0, stream>>>(w1 + 7168, bufW, 14336, 64);
  gemm_k<1><<<dim3(56, 16), 256, 0, stream>>>(xn, bufW, nullptr, ub, nullptr,
                                              nullptr, 4096, 4096, 14336, 7168);
  convw_k<<<dim3(56, 64), 256, 0, stream>>>(w3, bufW, 14336, 64);
  gemm_k<3><<<dim3(56, 16), 256, 0, stream>>>(xn, bufW, nullptr, ub, nullptr, ub,
                                              4096, 4096, 14336, 0);
  convw_k<<<dim3(56, 64), 256, 0, stream>>>(w3 + 7168, bufW, 14336, 64);
  gemm_k<3><<<dim3(56, 16), 256, 0, stream>>>(xn, bufW, nullptr, ub, nullptr, ub,
                                              4096, 4096, 14336, 7168);
  convw_k<<<dim3(32, 112), 256, 0, stream>>>(w2, bufW, 4096, 112);
  gemm_k<2><<<dim3(32, 16), 256, 0, stream>>>(ub, bufW, out, nullptr, hbuf,
                                              nullptr, 7168, 14336, 4096, 0);
  convw_k<<<dim3(32, 112), 256, 0, stream>>>(w2 + (size_t)7168 * 4096, bufW, 4096, 112);
  gemm_k<4><<<dim3(32, 16), 256, 0, stream>>>(ub + 7168, bufW, out, nullptr,
                                              nullptr, nullptr, 7168, 14336, 4096, 0);
}

// Round 19
// 1525.757 us; speedup vs baseline: 1.0109x; 1.0109x over previous
//
#include <hip/hip_runtime.h>

typedef _Float16 h16;
typedef _Float16 h16x4 __attribute__((ext_vector_type(4)));
typedef _Float16 h16x8 __attribute__((ext_vector_type(8)));
typedef __fp16 fp16x2 __attribute__((ext_vector_type(2)));
typedef float f32x4 __attribute__((ext_vector_type(4)));
typedef float f32x16 __attribute__((ext_vector_type(16)));
typedef unsigned short u16;
typedef unsigned int u32;
typedef unsigned int u32x4 __attribute__((ext_vector_type(4)));

__device__ __forceinline__ f32x4 mfma16(h16x8 a, h16x8 b, f32x4 c) {
  return __builtin_amdgcn_mfma_f32_16x16x32_f16(a, b, c, 0, 0, 0);
}
__device__ __forceinline__ f32x16 mfma32(h16x8 a, h16x8 b, f32x16 c) {
  return __builtin_amdgcn_mfma_f32_32x32x16_f16(a, b, c, 0, 0, 0);
}
__device__ __forceinline__ float fexp2(float x) {
#if __has_builtin(__builtin_amdgcn_exp2f)
  return __builtin_amdgcn_exp2f(x);
#else
  return exp2f(x);
#endif
}
__device__ __forceinline__ u32 pkh(float a, float b) {
  fp16x2 t = __builtin_amdgcn_cvt_pkrtz(a, b);
  return __builtin_bit_cast(u32, t);
}

typedef const __attribute__((address_space(1))) void* gas_p;
typedef __attribute__((address_space(3))) void* las_p;
__device__ __forceinline__ void ldscp16(const void* g, void* l) {
  __builtin_amdgcn_global_load_lds((gas_p)g, (las_p)l, 16, 0, 0);
}
#define VMCNT(n) asm volatile("s_waitcnt vmcnt(" #n ")" ::: "memory")
#define SBAR() asm volatile("s_barrier" ::: "memory")

// ---------------- RMSNorm: f32 [2048][4096] -> f16 ----------------
__global__ __launch_bounds__(256) void rmsnorm_k(
    const float* __restrict__ x, const float* __restrict__ w, h16* __restrict__ out) {
  const int row = blockIdx.x, t = threadIdx.x;
  const float* xr = x + (size_t)row * 4096;
  float4 v[4];
  float ss = 0.f;
#pragma unroll
  for (int j = 0; j < 4; j++) {
    v[j] = *(const float4*)(xr + 4 * t + 1024 * j);
    ss += v[j].x * v[j].x + v[j].y * v[j].y + v[j].z * v[j].z + v[j].w * v[j].w;
  }
#pragma unroll
  for (int off = 1; off < 64; off <<= 1) ss += __shfl_xor(ss, off, 64);
  __shared__ float red[4];
  if ((t & 63) == 0) red[t >> 6] = ss;
  __syncthreads();
  float scale = rsqrtf((red[0] + red[1] + red[2] + red[3]) * (1.f / 4096.f) + 1e-6f);
  h16* orow = out + (size_t)row * 4096;
#pragma unroll
  for (int j = 0; j < 4; j++) {
    float4 wv = *(const float4*)(w + 4 * t + 1024 * j);
    h16x4 o;
    o[0] = (h16)(v[j].x * scale * wv.x);
    o[1] = (h16)(v[j].y * scale * wv.y);
    o[2] = (h16)(v[j].z * scale * wv.z);
    o[3] = (h16)(v[j].w * scale * wv.w);
    *(h16x4*)(orow + 4 * t + 1024 * j) = o;
  }
}

// ------- weight convert: f32 -> f16 tiled+swizzled LDS images -------
__global__ __launch_bounds__(256) void convw_k(
    const float* __restrict__ W, h16* __restrict__ out, int rowN, int ktiles) {
  __shared__ u16 timg[8192];
  const int t = threadIdx.x, b = blockIdx.x, kt = blockIdx.y;
  const float* src = W + (size_t)(kt * 64) * rowN + b * 128;
#pragma unroll
  for (int i = 0; i < 8; i++) {
    int c = t + (i << 8);
    int krow = c >> 5, nc = (c & 31) << 2;
    float4 v = *(const float4*)(src + (size_t)krow * rowN + nc);
    int kc = krow >> 3, e = krow & 7;
    float vals[4] = {v.x, v.y, v.z, v.w};
#pragma unroll
    for (int j = 0; j < 4; j++) {
      int m = nc + j;
      h16 hv = (h16)vals[j];
      timg[(m << 6) + ((kc ^ (m & 7)) << 3) + e] = __builtin_bit_cast(u16, hv);
    }
  }
  __syncthreads();
  uint4* dst = (uint4*)(out + ((size_t)(b * ktiles + kt) << 13));
  const uint4* s4 = (const uint4*)timg;
#pragma unroll
  for (int i = 0; i < 4; i++) dst[t + (i << 8)] = s4[t + (i << 8)];
}

// -------- GEMM v17: 256 thr, BM=BN=128, BK=64, 2 dbuf (64KB -> 2 blocks/CU) --------
// Counted prefetch dist-2: issue(t+2) after compute-barrier; tile top VMCNT(8)+SBAR.
// EPI: 1 f16; 2 f32=resid+acc; 3 f16=silu(uin)*acc; 4 f32+=acc;
//      5 split: col<4096 -> f16 outH, else f32 outF (col-4096, ld 2048)
template <int EPI>
__global__ __launch_bounds__(256, 2) void gemm_k(
    const h16* __restrict__ A, const h16* __restrict__ Wt,
    float* outF, h16* outH, const float* resid, const h16* uin,
    int K, int lda, int ldo, int no0) {
  __shared__ u16 lds[2][16384];  // per buf 32KB: A[128][64] @0, B[128][64] @16KB
  const int tid = threadIdx.x, lane = tid & 63;
  const int wv = tid >> 6, wr = wv >> 1, wc = wv & 1;
  const int g = lane >> 4, lr = lane & 15;
  const int m0 = blockIdx.y << 7, n0 = blockIdx.x << 7;
  const int ktiles = K >> 6;

  f32x4 acc[4][4];
#pragma unroll
  for (int i = 0; i < 4; i++)
#pragma unroll
    for (int j = 0; j < 4; j++) acc[i][j] = {0.f, 0.f, 0.f, 0.f};

  const h16* gB = Wt + (((size_t)blockIdx.x * ktiles) << 13) + tid * 8;

  auto issue = [&](int t) {
    char* base = (char*)lds[t & 1];
#pragma unroll
    for (int i = 0; i < 4; i++) {
      int c = tid + (i << 8);
      int r = c >> 3, ch = (c & 7) ^ ((c >> 3) & 7);
      ldscp16(A + (size_t)(m0 + r) * lda + t * 64 + (ch << 3), base + c * 16);
    }
#pragma unroll
    for (int i = 0; i < 4; i++)
      ldscp16(gB + ((size_t)t << 13) + (i << 11), base + 16384 + tid * 16 + (i << 12));
  };

  issue(0);
  issue(1);

  for (int t = 0; t < ktiles; ++t) {
    if (t + 1 < ktiles) { VMCNT(8); } else { VMCNT(0); }
    SBAR();
    const char* bp = (const char*)lds[t & 1];
#pragma unroll
    for (int ks = 0; ks < 2; ++ks) {
      h16x8 av[4], bv[4];
      const int cc = (ks << 2) + g;
#pragma unroll
      for (int f = 0; f < 4; f++) {
        int row = (wr << 6) + (f << 4) + lr;
        av[f] = *(const h16x8*)(bp + row * 128 + ((cc ^ (row & 7)) << 4));
        int nr = (wc << 6) + (f << 4) + lr;
        bv[f] = *(const h16x8*)(bp + 16384 + nr * 128 + ((cc ^ (nr & 7)) << 4));
      }
      __builtin_amdgcn_s_setprio(1);
#pragma unroll
      for (int fi = 0; fi < 4; fi++)
#pragma unroll
        for (int fj = 0; fj < 4; fj++)
          acc[fi][fj] = mfma16(av[fi], bv[fj], acc[fi][fj]);
      __builtin_amdgcn_s_setprio(0);
    }
    SBAR();
    if (t + 2 < ktiles) issue(t + 2);
  }
  // epilogue; C/D: col=lane&15, row=(lane>>4)*4+r
#pragma unroll
  for (int fi = 0; fi < 4; fi++) {
    const int row = m0 + (wr << 6) + (fi << 4) + (g << 2);
#pragma unroll
    for (int fj = 0; fj < 4; fj++) {
      const int col = no0 + n0 + (wc << 6) + (fj << 4) + lr;
#pragma unroll
      for (int r = 0; r < 4; r++) {
        float vl = acc[fi][fj][r];
        if constexpr (EPI == 5) {
          if (col < 4096) outH[(size_t)(row + r) * 4096 + col] = (h16)vl;
          else outF[(size_t)(row + r) * 2048 + (col - 4096)] = vl;
        } else {
          size_t idx = (size_t)(row + r) * ldo + col;
          if constexpr (EPI == 1) outH[idx] = (h16)vl;
          else if constexpr (EPI == 2) outF[idx] = resid[idx] + vl;
          else if constexpr (EPI == 3) {
            float u = (float)uin[idx];
            outH[idx] = (h16)((u / (1.f + __expf(-u))) * vl);
          } else outF[idx] = outF[idx] + vl;
        }
      }
    }
  }
}

// ---------------- RoPE on Q (f16, in-place safe), folds softmax scale ----------
__global__ __launch_bounds__(256) void rope_q_k(
    const h16* __restrict__ qin, const float* __restrict__ freqs, h16* qout) {
  const int row = blockIdx.x, t = threadIdx.x;
  const float SCL = 0.12751743647239037f;  // 1/sqrt(128)*log2(e)
#pragma unroll
  for (int it = 0; it < 8; ++it) {
    int pid = t + 256 * it;
    int head = pid >> 6, pp = pid & 63;
    size_t idx = (size_t)row * 4096 + head * 128 + 2 * pp;
    float x0 = (float)qin[idx], x1 = (float)qin[idx + 1];
    float cs = freqs[row * 128 + 2 * pp], sn = freqs[row * 128 + 2 * pp + 1];
    qout[idx] = (h16)((x0 * cs - x1 * sn) * SCL);
    qout[idx + 1] = (h16)((x0 * sn + x1 * cs) * SCL);
  }
}

// ------- build new cache: f32 outs + f16 K [kvh][r][d] + f16 V^T [kvh][d][r] -------
__global__ __launch_bounds__(256) void cache_build_k(
    const float* __restrict__ oldK, const float* __restrict__ oldV,
    const float* __restrict__ kvraw, const float* __restrict__ freqs,
    float* __restrict__ outK, float* __restrict__ outV,
    h16* __restrict__ Kf, h16* __restrict__ Vt) {
  const int rt = blockIdx.x, kvh = blockIdx.y;
  const int r0 = rt * 64, tid = threadIdx.x;
  __shared__ u16 vtile[64][128];
#pragma unroll
  for (int it = 0; it < 16; ++it) {
    int s = tid + 256 * it;
    int rr = s >> 6, pp = s & 63;
    int r = r0 + rr;
    float k0, k1, v0, v1;
    if (r < 2048) {
      const float* kp = oldK + (size_t)(r + 2048) * 1024 + kvh * 128 + 2 * pp;
      k0 = kp[0]; k1 = kp[1];
      const float* vp = oldV + (size_t)(r + 2048) * 1024 + kvh * 128 + 2 * pp;
      v0 = vp[0]; v1 = vp[1];
    } else {
      int tpos = r - 2048;
      const float* kp = kvraw + (size_t)tpos * 2048 + kvh * 128 + 2 * pp;
      float x0 = kp[0], x1 = kp[1];
      float cs = freqs[tpos * 128 + 2 * pp], sn = freqs[tpos * 128 + 2 * pp + 1];
      k0 = x0 * cs - x1 * sn;
      k1 = x0 * sn + x1 * cs;
      const float* vp = kvraw + (size_t)tpos * 2048 + 1024 + kvh * 128 + 2 * pp;
      v0 = vp[0]; v1 = vp[1];
    }
    size_t oidx = (size_t)r * 1024 + kvh * 128 + 2 * pp;
    outK[oidx] = k0; outK[oidx + 1] = k1;
    outV[oidx] = v0; outV[oidx + 1] = v1;
    size_t kfi = (size_t)kvh * 524288 + (size_t)r * 128 + 2 * pp;
    Kf[kfi] = (h16)k0; Kf[kfi + 1] = (h16)k1;
    h16 h0 = (h16)v0, h1 = (h16)v1;
    vtile[rr][2 * pp] = __builtin_bit_cast(u16, h0);
    vtile[rr][2 * pp + 1] = __builtin_bit_cast(u16, h1);
  }
  __syncthreads();
#pragma unroll
  for (int it = 0; it < 4; ++it) {
    int c = tid + 256 * it;
    int d = c >> 3, rg = c & 7;
    u16 tmp[8];
#pragma unroll
    for (int u = 0; u < 8; u++) tmp[u] = vtile[rg * 8 + u][d];
    *(uint4*)((u16*)Vt + (size_t)kvh * 524288 + (size_t)d * 4096 + r0 + rg * 8) =
        *(uint4*)tmp;
  }
}

// -------- flash attention v5: 256 thr, QBLK=128, 2-buf, split counted vmcnt --------
__global__ __launch_bounds__(256, 2) void attn_k(
    const h16* __restrict__ Q, const h16* __restrict__ Kf,
    const h16* __restrict__ Vt, h16* __restrict__ O) {
  __shared__ u16 skv[2][16384];  // per buf: K[64 j][128 d] @0, V[128 d][64 j] @16KB
  const int qt = 15 - blockIdx.x, h = blockIdx.y;
  const int q0 = qt << 7, kvh = h >> 2;
  const int tid = threadIdx.x, w = tid >> 6, lane = tid & 63;
  const int lq = lane & 31, lh = lane >> 5;
  const h16* Kb = Kf + (size_t)kvh * 524288;
  const h16* Vb = Vt + (size_t)kvh * 524288;
  const int qg = q0 + w * 32 + lq;

  h16x8 qv[8];
  {
    const h16* qp = Q + (size_t)qg * 4096 + h * 128 + (lh << 3);
#pragma unroll
    for (int c = 0; c < 8; c++) qv[c] = *(const h16x8*)(qp + c * 16);
  }
  h16x8 hone;
#pragma unroll
  for (int i = 0; i < 8; i++) hone[i] = (h16)1.0f;
  f32x16 oa[4], ol2;
#pragma unroll
  for (int d = 0; d < 4; d++)
#pragma unroll
    for (int v = 0; v < 16; v++) oa[d][v] = 0.f;
#pragma unroll
  for (int v = 0; v < 16; v++) ol2[v] = 0.f;
  float m2 = -3e38f;
  const int ntiles = 34 + 2 * qt;

  const int jK = tid >> 4, kch = tid & 15;
  const h16* gK = Kb + (size_t)jK * 128 + ((kch ^ (jK & 15)) << 3);
  const int dV = tid >> 3, jch = tid & 7;
  const h16* gV = Vb + (size_t)dV * 4096 + ((jch ^ (dV & 7)) << 3);

  auto issueK = [&](int jt) {
    char* base = (char*)skv[jt & 1];
    const h16* s = gK + (size_t)(jt << 6) * 128;
#pragma unroll
    for (int i = 0; i < 4; i++)
      ldscp16(s + (size_t)i * 2048, base + tid * 16 + i * 4096);
  };
  auto issueV = [&](int jt) {
    char* base = (char*)skv[jt & 1] + 16384;
    const h16* s = gV + (jt << 6);
#pragma unroll
    for (int i = 0; i < 4; i++)
      ldscp16(s + (size_t)i * 131072, base + tid * 16 + i * 4096);
  };

  issueK(0); issueV(0);
  VMCNT(0);
  SBAR();

  for (int jt = 0; jt < ntiles; ++jt) {
    const char* bp = (const char*)skv[jt & 1];
    const bool more = (jt + 1 < ntiles);
    if (more) issueK(jt + 1);
    f32x16 st[2];
#pragma unroll
    for (int jb = 0; jb < 2; jb++) {
      f32x16 s;
#pragma unroll
      for (int v = 0; v < 16; v++) s[v] = 0.f;
      const int jr = jb * 32 + lq;
      __builtin_amdgcn_s_setprio(1);
#pragma unroll
      for (int kc = 0; kc < 8; kc++) {
        h16x8 ak =
            *(const h16x8*)(bp + jr * 256 + ((((kc << 1) + lh) ^ (jr & 15)) << 4));
        s = mfma32(ak, qv[kc], s);
      }
      __builtin_amdgcn_s_setprio(0);
      st[jb] = s;
    }
    if (more) issueV(jt + 1);
    if (jt >= ntiles - 2) {
      const int j0 = jt << 6;
#pragma unroll
      for (int jb = 0; jb < 2; jb++)
#pragma unroll
        for (int v = 0; v < 16; v++) {
          int j = j0 + jb * 32 + (v & 3) + (((v >> 2) & 3) << 3) + (lh << 2);
          if (j > 2048 + qg) st[jb][v] = -1e30f;
        }
    }
    float pm = fmaxf(st[0][0], st[0][1]);
#pragma unroll
    for (int v = 2; v < 16; v += 2) pm = fmaxf(fmaxf(st[0][v], st[0][v + 1]), pm);
#pragma unroll
    for (int v = 0; v < 16; v += 2) pm = fmaxf(fmaxf(st[1][v], st[1][v + 1]), pm);
    pm = fmaxf(pm, __shfl_xor(pm, 32, 64));
    if (__any(pm - m2 > 8.f)) {
      float mn = fmaxf(m2, pm);
      float al = fexp2(m2 - mn);
      m2 = mn;
#pragma unroll
      for (int d = 0; d < 4; d++) oa[d] *= al;
      ol2 *= al;
    }
    u32 pw[2][8];
#pragma unroll
    for (int jb = 0; jb < 2; jb++)
#pragma unroll
      for (int c = 0; c < 4; c++) {
        float p0 = fexp2(st[jb][4 * c] - m2);
        float p1 = fexp2(st[jb][4 * c + 1] - m2);
        float p2 = fexp2(st[jb][4 * c + 2] - m2);
        float p3 = fexp2(st[jb][4 * c + 3] - m2);
        pw[jb][2 * c] = pkh(p0, p1);
        pw[jb][2 * c + 1] = pkh(p2, p3);
      }
    h16x8 pb[4];
#pragma unroll
    for (int kc = 0; kc < 4; kc++) {
      const int jb = kc >> 1, cb = (kc & 1) << 1;
      u32 oa_ = pw[jb][2 * cb], ob_ = pw[jb][2 * cb + 1];
      u32 oc_ = pw[jb][2 * cb + 2], od_ = pw[jb][2 * cb + 3];
      u32 s0 = lh ? oa_ : oc_, s1 = lh ? ob_ : od_;
      u32 r0 = __shfl_xor(s0, 32, 64), r1 = __shfl_xor(s1, 32, 64);
      u32x4 wds = {lh ? r0 : oa_, lh ? r1 : ob_, lh ? oc_ : r0, lh ? od_ : r1};
      pb[kc] = __builtin_bit_cast(h16x8, wds);
    }
    // V(jt) ready gate: oldest-4 of {V(jt), K(jt+1), V(jt+1)} = V(jt)
    if (more) { VMCNT(8); } else { VMCNT(0); }
    __builtin_amdgcn_s_setprio(1);
#pragma unroll
    for (int d = 0; d < 4; d++) {
      const int dr = (d << 5) + lq;
#pragma unroll
      for (int kc = 0; kc < 4; kc++) {
        h16x8 av = *(const h16x8*)(bp + 16384 + dr * 128 +
                                   ((((kc << 1) + lh) ^ (dr & 7)) << 4));
        oa[d] = mfma32(av, pb[kc], oa[d]);
      }
    }
#pragma unroll
    for (int kc = 0; kc < 4; kc++) ol2 = mfma32(hone, pb[kc], ol2);
    __builtin_amdgcn_s_setprio(0);
    if (more) {
      VMCNT(4);  // K(jt+1) ready; V(jt+1) stays in flight across barrier
      SBAR();
    }
  }
  float rl = 1.f / ol2[0];
  h16* Op = O + (size_t)qg * 4096 + h * 128;
#pragma unroll
  for (int d = 0; d < 4; d++)
#pragma unroll
    for (int b = 0; b < 4; b++) {
      h16x4 ov;
#pragma unroll
      for (int i = 0; i < 4; i++) ov[i] = (h16)(oa[d][(b << 2) + i] * rl);
      *(h16x4*)(Op + (d << 5) + (b << 3) + (lh << 2)) = ov;
    }
}

extern "C" void kernel_launch(void* const* d_in, const int* in_sizes, int n_in,
                              void* d_out, int out_size, void* d_ws, size_t ws_size,
                              hipStream_t stream) {
  const float* x = (const float*)d_in[0];
  const float* freqs = (const float*)d_in[2];
  const float* oldK = (const float*)d_in[3];
  const float* oldV = (const float*)d_in[4];
  const float* wq = (const float*)d_in[5];
  const float* wk = (const float*)d_in[6];
  const float* wvp = (const float*)d_in[7];
  const float* wo = (const float*)d_in[8];
  const float* w1 = (const float*)d_in[9];
  const float* w2 = (const float*)d_in[10];
  const float* w3 = (const float*)d_in[11];
  const float* anw = (const float*)d_in[12];
  const float* fnw = (const float*)d_in[13];
  float* out = (float*)d_out;
  float* outK = out + 8388608;
  float* outV = out + 12582912;

  char* ws = (char*)d_ws;
  h16* xn = (h16*)(ws + 0);                // 16.78 MB f16 [2048][4096]
  h16* bufW = (h16*)(ws + 16777216);       // 58.72 MB tiled f16 weights (reused)
  float* hbuf = (float*)(ws + 75497472);   // 33.55 MB f32 [2048][4096]
  float* kvraw = (float*)(ws + 75497472);  // 16.78 MB f32 [2048][2048] (aliased)
  h16* kf = (h16*)(ws + 92274688);         //  8.39 MB
  h16* vt = (h16*)(ws + 100663296);        //  8.39 MB
  h16* ub = (h16*)(ws + 109051904);        // 58.72 MB f16 [2048][14336]
  h16* qraw = (h16*)(ws + 109051904);      // 16.78 MB (aliased in ub span)
  h16* attnb = (h16*)(ws + 125829120);     // 16.78 MB (aliased in ub span)

  // attention path
  rmsnorm_k<<<2048, 256, 0, stream>>>(x, anw, xn);
  convw_k<<<dim3(32, 64), 256, 0, stream>>>(wq, bufW, 4096, 64);
  convw_k<<<dim3(8, 64), 256, 0, stream>>>(wk, bufW + ((size_t)32 * 64 << 13), 1024, 64);
  convw_k<<<dim3(8, 64), 256, 0, stream>>>(wvp, bufW + ((size_t)40 * 64 << 13), 1024, 64);
  gemm_k<5><<<dim3(48, 16), 256, 0, stream>>>(xn, bufW, kvraw, qraw, nullptr,
                                              nullptr, 4096, 4096, 0, 0);
  rope_q_k<<<2048, 256, 0, stream>>>(qraw, freqs, qraw);
  cache_build_k<<<dim3(64, 8), 256, 0, stream>>>(oldK, oldV, kvraw, freqs, outK,
                                                 outV, kf, vt);
  attn_k<<<dim3(16, 32), 256, 0, stream>>>(qraw, kf, vt, attnb);
  convw_k<<<dim3(32, 64), 256, 0, stream>>>(wo, bufW, 4096, 64);
  gemm_k<2><<<dim3(32, 16), 256, 0, stream>>>(attnb, bufW, hbuf, nullptr, x,
                                              nullptr, 4096, 4096, 4096, 0);
  // FFN path
  rmsnorm_k<<<2048, 256, 0, stream>>>(hbuf, fnw, xn);
  convw_k<<<dim3(56, 64), 256, 0, stream>>>(w1, bufW, 14336, 64);
  gemm_k<1><<<dim3(56, 16), 256, 0, stream>>>(xn, bufW, nullptr, ub, nullptr,
                                              nullptr, 4096, 4096, 14336, 0);
  convw_k<<<dim3(56, 64), 256, 0, stream>>>(w1 + 7168, bufW, 14336, 64);
  gemm_k<1><<<dim3(56, 16), 256, 0, stream>>>(xn, bufW, nullptr, ub, nullptr,
                                              nullptr, 4096, 4096, 14336, 7168);
  convw_k<<<dim3(56, 64), 256, 0, stream>>>(w3, bufW, 14336, 64);
  gemm_k<3><<<dim3(56, 16), 256, 0, stream>>>(xn, bufW, nullptr, ub, nullptr, ub,
                                              4096, 4096, 14336, 0);
  convw_k<<<dim3(56, 64), 256, 0, stream>>>(w3 + 7168, bufW, 14336, 64);
  gemm_k<3><<<dim3(56, 16), 256, 0, stream>>>(xn, bufW, nullptr, ub, nullptr, ub,
                                              4096, 4096, 14336, 7168);
  convw_k<<<dim3(32, 112), 256, 0, stream>>>(w2, bufW, 4096, 112);
  gemm_k<2><<<dim3(32, 16), 256, 0, stream>>>(ub, bufW, out, nullptr, hbuf,
                                              nullptr, 7168, 14336, 4096, 0);
  convw_k<<<dim3(32, 112), 256, 0, stream>>>(w2 + (size_t)7168 * 4096, bufW, 4096, 112);
  gemm_k<4><<<dim3(32, 16), 256, 0, stream>>>(ub + 7168, bufW, out, nullptr,
                                              nullptr, nullptr, 7168, 14336, 4096, 0);
}